// Round 11
// baseline (274.093 us; speedup 1.0000x reference)
//
#include <hip/hip_runtime.h>
#include <math.h>

#define NB   8
#define SS   1024
#define DD   512
#define HH   8
#define DKK  64
#define NEGF (-3.0e38f)
// score scale folded with log2(e): exp(x) == exp2(x*log2e)
#define SC   (0.125f * 1.4426950408889634f)

// OCCUPANCY LEDGER (R0-R10): residency driver is reported VGPR_Count.
// <=32 -> 2 blk/CU; 36-40 -> 1 blk/CU (~1.25x cost). LDS up to 68.6KB has
// NO residency effect at low VGPR (R10: 68,608B @ VGPR28 -> occ 52.8%).
// R10 = best attn: single-barrier Phase 1 (dynamic #pragma unroll 1 loop,
// short live ranges) + R9 Phase 2 (no cs[16]) -> 157.5us. attn FROZEN.
// R11 targets the ~115us non-attn residual: GEMMs at K=512/BK=32 are
// barrier-drain-bound (16 steps x 2 full vmcnt drains); BK=64 halves steps.
#define QSTR 88             // halves; q tile stride
#define SCHUNK (16 * 256)   // floats per score chunk buffer (XOR swizzled)
#define PSTR 280            // halves; attn p rows (phase 3, aliased)

typedef _Float16 half8 __attribute__((ext_vector_type(8)));
typedef float    f32x4 __attribute__((ext_vector_type(4)));

// async 16B/lane global->LDS (wave-uniform LDS base + lane*16)
#define GLDS16(g, l) __builtin_amdgcn_global_load_lds( \
    (const __attribute__((address_space(1))) void*)(g), \
    (__attribute__((address_space(3))) void*)(l), 16, 0, 0)

// ---------------------------------------------------------------------------
// DPP helpers: full-rate VALU cross-lane (no ds_bpermute).
// ---------------------------------------------------------------------------
template<int CTRL, int RM, int BM, bool BC>
__device__ __forceinline__ float dpp_f(float x) {
    return __builtin_bit_cast(float,
        __builtin_amdgcn_update_dpp(0, __builtin_bit_cast(int, x),
                                    CTRL, RM, BM, BC));
}

// inclusive 64-lane prefix sum: row_shr 1/2/4/8 then row_bcast:15 (rows 1,3)
// and row_bcast:31 (rows 2,3). old=0 so masked/invalid lanes add 0.
__device__ __forceinline__ float scan64(float x) {
    x += dpp_f<0x111, 0xf, 0xf, true >(x);   // row_shr:1
    x += dpp_f<0x112, 0xf, 0xf, true >(x);   // row_shr:2
    x += dpp_f<0x114, 0xf, 0xf, true >(x);   // row_shr:4
    x += dpp_f<0x118, 0xf, 0xf, true >(x);   // row_shr:8
    x += dpp_f<0x142, 0xa, 0xf, false>(x);   // row_bcast:15 -> rows 1,3
    x += dpp_f<0x143, 0xc, 0xf, false>(x);   // row_bcast:31 -> rows 2,3
    return x;
}

__device__ __forceinline__ float redsum64(float x) {
    x += dpp_f<0xB1,  0xf, 0xf, true>(x);    // quad_perm [1,0,3,2]  (xor 1)
    x += dpp_f<0x4E,  0xf, 0xf, true>(x);    // quad_perm [2,3,0,1]  (xor 2)
    x += dpp_f<0x141, 0xf, 0xf, true>(x);    // row_half_mirror      (xor 4)
    x += dpp_f<0x140, 0xf, 0xf, true>(x);    // row_mirror           (xor 8)
    x += __shfl_xor(x, 16);
    x += __shfl_xor(x, 32);
    return x;
}

__device__ __forceinline__ float bcast63(float x) {
    return __builtin_bit_cast(float,
        __builtin_amdgcn_readlane(__builtin_bit_cast(int, x), 63));
}

// ---------------------------------------------------------------------------
// cvt: x, Wk, Wv, Wo (fp32) -> fp16 buffers. 8 elems/thread.
// ---------------------------------------------------------------------------
__global__ __launch_bounds__(256) void cvt_fp16(
    const float* __restrict__ x,  _Float16* __restrict__ xh,
    const float* __restrict__ wk, _Float16* __restrict__ wkh,
    const float* __restrict__ wv, _Float16* __restrict__ wvh,
    const float* __restrict__ wo, _Float16* __restrict__ woh)
{
    const size_t NX = (size_t)NB * SS * DD;   // 4194304
    const size_t NW = (size_t)DD * DD;        // 262144
    size_t f = ((size_t)blockIdx.x * 256 + threadIdx.x) * 8;
    const float* src; _Float16* dst; size_t off;
    if (f < NX)               { src = x;  dst = xh;  off = f; }
    else if (f < NX + NW)     { src = wk; dst = wkh; off = f - NX; }
    else if (f < NX + 2*NW)   { src = wv; dst = wvh; off = f - NX - 2*NW + NW; }
    else                      { src = wo; dst = woh; off = f - NX - 2*NW; }
    float4 f0 = *(const float4*)&src[off];
    float4 f1 = *(const float4*)&src[off + 4];
    half8 hv = {(_Float16)f0.x,(_Float16)f0.y,(_Float16)f0.z,(_Float16)f0.w,
                (_Float16)f1.x,(_Float16)f1.y,(_Float16)f1.z,(_Float16)f1.w};
    *(half8*)&dst[off] = hv;
}

// ---------------------------------------------------------------------------
// GEMM #1 — R11: BK=64 (8 K-steps instead of 16; half the vmcnt-drain
// barrier pairs; total DMA instrs, MFMA count, and k-accumulation order
// bit-identical to BK=32). 128x128 tile, global_load_lds staging.
// q = xh@Wk^T + bk -> fp16 [b,h,s,dk]; v = xh@Wv^T + bv -> fp16 [b,h,dk,s].
// ---------------------------------------------------------------------------
__global__ __launch_bounds__(256) void gemm_qv(
    const _Float16* __restrict__ xh,
    const _Float16* __restrict__ wkh, const float* __restrict__ bk,
    const _Float16* __restrict__ wvh, const float* __restrict__ bv,
    _Float16* __restrict__ q_ws, _Float16* __restrict__ vt_ws)
{
    __shared__ __align__(16) _Float16 Ah[128 * 64];   // 16 KB, packed
    __shared__ __align__(16) _Float16 Bh[128 * 64];

    const int m0  = blockIdx.x * 128;
    const int n0c = blockIdx.y * 128;
    const bool is_v = (n0c >= DD);
    const _Float16* __restrict__ Wp = is_v ? wvh : wkh;
    const float*    __restrict__ bp = is_v ? bv : bk;
    const int n0 = n0c & (DD - 1);

    const int tid  = threadIdx.x;
    const int w    = tid >> 6;
    const int lane = tid & 63;
    const int quad = lane >> 4;
    const int n    = lane & 15;
    const int wm   = w >> 1, wn = w & 1;

    f32x4 acc[4][4] = {};

    for (int k0 = 0; k0 < DD; k0 += 64) {
        __syncthreads();   // prior frag reads done
        #pragma unroll
        for (int c = 0; c < 4; ++c) {
            // ci covers 128 rows x 64 cols: row = ci>>3, col8 = (ci&7)*8
            const int ci = (w * 4 + c) * 64 + lane;
            const int r  = ci >> 3;
            const int co = (ci & 7) * 8;
            GLDS16(&xh[(size_t)(m0 + r) * DD + k0 + co], &Ah[(w * 4 + c) * 512]);
            GLDS16(&Wp[(size_t)(n0 + r) * DD + k0 + co], &Bh[(w * 4 + c) * 512]);
        }
        __syncthreads();   // compiler drains vmcnt before barrier
        #pragma unroll
        for (int kf = 0; kf < 2; ++kf) {
            half8 af[4], bf[4];
            #pragma unroll
            for (int mi = 0; mi < 4; ++mi)
                af[mi] = *(const half8*)&Ah[(wm*64 + mi*16 + n) * 64 + kf*32 + quad*8];
            #pragma unroll
            for (int ni = 0; ni < 4; ++ni)
                bf[ni] = *(const half8*)&Bh[(wn*64 + ni*16 + n) * 64 + kf*32 + quad*8];
            #pragma unroll
            for (int mi = 0; mi < 4; ++mi)
                #pragma unroll
                for (int ni = 0; ni < 4; ++ni)
                    acc[mi][ni] = __builtin_amdgcn_mfma_f32_16x16x32_f16(
                        af[mi], bf[ni], acc[mi][ni], 0, 0, 0);
        }
    }

    #pragma unroll
    for (int mi = 0; mi < 4; ++mi) {
        #pragma unroll
        for (int ni = 0; ni < 4; ++ni) {
            const int col = n0 + wn*64 + ni*16 + n;   // 0..511
            const int h   = col >> 6;
            const int dk  = col & 63;
            const float bias = bp[col];
            const int gbase = m0 + wm*64 + mi*16 + quad*4;
            const int bidx  = gbase >> 10;
            const int sr    = gbase & (SS - 1);
            if (!is_v) {
                #pragma unroll
                for (int reg = 0; reg < 4; ++reg)
                    q_ws[((size_t)(bidx * HH + h) * SS + sr + reg) * DKK + dk] =
                        (_Float16)(acc[mi][ni][reg] + bias);
            } else {
                _Float16 h4[4];
                #pragma unroll
                for (int reg = 0; reg < 4; ++reg)
                    h4[reg] = (_Float16)(acc[mi][ni][reg] + bias);
                *(uint2*)&vt_ws[((size_t)(bidx * HH + h) * DKK + dk) * SS + sr] =
                    *(uint2*)h4;
            }
        }
    }
}

// ---------------------------------------------------------------------------
// GEMM #2 — R11: BK=64 (same halved-barrier rationale as gemm_qv).
// out = attn_h @ Wo^T + bo (A fp16 from attn, out fp32)
// ---------------------------------------------------------------------------
__global__ __launch_bounds__(256) void gemm_out(
    const _Float16* __restrict__ A,
    const _Float16* __restrict__ woh, const float* __restrict__ bo,
    float* __restrict__ out)
{
    __shared__ __align__(16) _Float16 Ah[128 * 64];
    __shared__ __align__(16) _Float16 Bh[128 * 64];

    const int m0 = blockIdx.x * 128;
    const int n0 = blockIdx.y * 128;

    const int tid  = threadIdx.x;
    const int w    = tid >> 6;
    const int lane = tid & 63;
    const int quad = lane >> 4;
    const int n    = lane & 15;
    const int wm   = w >> 1, wn = w & 1;

    f32x4 acc[4][4] = {};

    for (int k0 = 0; k0 < DD; k0 += 64) {
        __syncthreads();
        #pragma unroll
        for (int c = 0; c < 4; ++c) {
            const int ci = (w * 4 + c) * 64 + lane;
            const int r  = ci >> 3;
            const int co = (ci & 7) * 8;
            GLDS16(&A[(size_t)(m0 + r) * DD + k0 + co],   &Ah[(w * 4 + c) * 512]);
            GLDS16(&woh[(size_t)(n0 + r) * DD + k0 + co], &Bh[(w * 4 + c) * 512]);
        }
        __syncthreads();
        #pragma unroll
        for (int kf = 0; kf < 2; ++kf) {
            half8 af[4], bf[4];
            #pragma unroll
            for (int mi = 0; mi < 4; ++mi)
                af[mi] = *(const half8*)&Ah[(wm*64 + mi*16 + n) * 64 + kf*32 + quad*8];
            #pragma unroll
            for (int ni = 0; ni < 4; ++ni)
                bf[ni] = *(const half8*)&Bh[(wn*64 + ni*16 + n) * 64 + kf*32 + quad*8];
            #pragma unroll
            for (int mi = 0; mi < 4; ++mi)
                #pragma unroll
                for (int ni = 0; ni < 4; ++ni)
                    acc[mi][ni] = __builtin_amdgcn_mfma_f32_16x16x32_f16(
                        af[mi], bf[ni], acc[mi][ni], 0, 0, 0);
        }
    }

    #pragma unroll
    for (int mi = 0; mi < 4; ++mi) {
        #pragma unroll
        for (int ni = 0; ni < 4; ++ni) {
            const int col  = n0 + wn*64 + ni*16 + n;
            const float bias = bo[col];
            const int gbase = m0 + wm*64 + mi*16 + quad*4;
            #pragma unroll
            for (int reg = 0; reg < 4; ++reg)
                out[(size_t)(gbase + reg) * DD + col] = acc[mi][ni][reg] + bias;
        }
    }
}

// ---------------------------------------------------------------------------
// MFMA attention — R10 body, FROZEN (157.5us, VGPR 28, 2 blk/CU):
// single-barrier Phase 1 (#pragma unroll 1 dynamic loop, per-chunk buffers),
// swapped-operand QK^T, XOR swizzle, R9 Phase 2 (no cs[16]), flat PV.
// Known-toxic (do not retry): forced 2-blk/CU launch_bounds (R3, spill);
// reported VGPR > 32 (R5-R8); sched_barrier-pinned raw barriers + manual
// cross-barrier prefetch (R5, m141); 16-wave PV + o_red; utT fold + tmax;
// 8-wave blocks (old session).
// ---------------------------------------------------------------------------
__global__ __launch_bounds__(1024) void attn_mfma(
    const _Float16* __restrict__ q,   // [B,H,S,DK] fp16 (K = Q)
    const _Float16* __restrict__ vt,  // [B,H,DK,S] fp16 (V transposed)
    const float* __restrict__ utT,    // [B,S,S]
    const float* __restrict__ gammas, // [H]
    _Float16* __restrict__ attn)      // [B,S,H,DK] fp16
{
    // phase 1: 4 x SCHUNK f32 = 65536 B; phase 3 aliases 4x16xPSTR halves
    // (35840 B) inside it. + q_lds 2816 B = 68352 B total.
    __shared__ __align__(16) unsigned char smem[4 * SCHUNK * 4];
    __shared__ __align__(16) _Float16 q_lds[16 * QSTR];
    float*    s_lds = (float*)smem;
    _Float16* p_lds = (_Float16*)smem;

    const int tid  = threadIdx.x;
    const int w    = tid >> 6;
    const int lane = tid & 63;
    const int quad = lane >> 4;
    const int n    = lane & 15;
    const int bh   = blockIdx.y;
    const int b    = bh >> 3;
    const int h    = bh & 7;
    // heavy-first (LPT): largest r0 dispatched first, light blocks fill tail
    const int r0   = ((SS / 16 - 1) - blockIdx.x) * 16;

    const _Float16* __restrict__ kq  = q  + (size_t)bh * SS * DKK;
    const _Float16* __restrict__ vtp = vt + (size_t)bh * DKK * SS;

    const int nchunk = (r0 + 16 + 255) >> 8;   // 1..4, block-uniform
    const int nt     = nchunk * 4;
    const int i_lane = r0 + n;   // q-row owned by this lane in phase 1

    // stage Q tile into LDS (keeps qa fragments out of long-lived VGPRs)
    if (tid < 256) {
        const int row = tid >> 4;
        const int c   = tid & 15;
        *(uint2*)&q_lds[row * QSTR + c * 4] =
            *(const uint2*)&kq[(size_t)(r0 + row) * DKK + c * 4];
    }
    __syncthreads();

    const float* __restrict__ utrow = &utT[((size_t)b * SS + i_lane) * SS];
    const int scol = (w * 16 + quad * 4) ^ ((n & 7) << 2);   // store swizzle
    const int pcol = lane ^ ((w & 7) << 2);                  // pull swizzle

    // ---- Phase 1: dynamic loop, per-chunk buffers, NO inter-chunk barrier
    #pragma unroll 1
    for (int c0 = 0; c0 < nchunk; ++c0) {
        const int jbase = c0 * 256 + w * 16;
        f32x4 v;
        if (jbase <= r0 + 15) {        // wave-uniform guard
            half8 qa0 = *(const half8*)&q_lds[n * QSTR + quad * 8];
            half8 qa1 = *(const half8*)&q_lds[n * QSTR + 32 + quad * 8];
            const _Float16* krow = &kq[(size_t)(jbase + n) * DKK];
            half8 k0 = *(const half8*)&krow[quad * 8];
            half8 k1 = *(const half8*)&krow[32 + quad * 8];
            f32x4 ut = *(const f32x4*)&utrow[jbase + quad * 4];
            f32x4 d = {0.f, 0.f, 0.f, 0.f};
            d = __builtin_amdgcn_mfma_f32_16x16x32_f16(k0, qa0, d, 0, 0, 0);
            d = __builtin_amdgcn_mfma_f32_16x16x32_f16(k1, qa1, d, 0, 0, 0);
            #pragma unroll
            for (int reg = 0; reg < 4; ++reg) {
                const int j = jbase + quad * 4 + reg;
                v[reg] = (j <= i_lane) ? d[reg] * SC * ut[reg] : NEGF;
            }
        } else {
            v = (f32x4){NEGF, NEGF, NEGF, NEGF};
        }
        *(f32x4*)&s_lds[c0 * SCHUNK + n * 256 + scol] = v;
    }
    __syncthreads();   // ONE barrier for the whole phase

    float sreg[16];
    #pragma unroll
    for (int c0 = 0; c0 < 4; ++c0) {
        if (c0 < nchunk) {
            #pragma unroll
            for (int ttl = 0; ttl < 4; ++ttl)
                sreg[c0 * 4 + ttl] =
                    s_lds[c0 * SCHUNK + w * 256 + ttl * 64 + pcol];
        }
    }

    // ---- Phase 2 ----
    const int i_row = r0 + w;
    const int ntw_u = (i_row >> 6) + 1;          // tiles intersecting causal
    const int ntw   = (nt < ntw_u) ? nt : ntw_u; // wave-uniform

    // pass A: z1 = row total of e — plain sum per lane + one butterfly.
    float z1acc = 0.f;
    #pragma unroll
    for (int t2 = 0; t2 < 16; ++t2)
        if (t2 < ntw) z1acc += __builtin_amdgcn_exp2f(sreg[t2]);
    const float z1     = redsum64(z1acc);
    const float inv_z1 = 1.0f / z1;

    const float g     = gammas[h];
    const float gl2   = -log1pf(__expf(g)) * 1.4426950408889634f; // gamma*log2e
    const float flane = (float)lane;

    // pass B: inline scan (e recomputed bit-identically), decay, numerator
    float carry = 0.f;
    float z2 = 0.f;
    #pragma unroll
    for (int t2 = 0; t2 < 16; ++t2) {
        if (t2 < ntw) {
            const float e  = __builtin_amdgcn_exp2f(sreg[t2]); // masked -> 0
            const float xv = scan64(e);
            const float cs = carry + xv;
            carry += bcast63(xv);
            const float pe = (float)(i_row - t2 * 64) - flane;  // <0 only masked
            const float dd = fmaxf((z1 - cs) * pe, 0.0f) * inv_z1;
            float te = __builtin_amdgcn_exp2f(__builtin_amdgcn_sqrtf(dd) * gl2);
            te = fmaxf(te, 1e-5f);            // gamma<0 -> te<=1, no hi clamp
            const float p = __builtin_amdgcn_exp2f(sreg[t2] * te); // masked -> 0
            sreg[t2] = p;
            z2 += p;
        } else {
            sreg[t2] = 0.f;                   // tiles beyond causal extent
        }
    }
    z2 = redsum64(z2);
    const float inv_z2 = 1.0f / z2;

    __syncthreads();   // all phase-1 s_lds pulls complete before p writes

    // ---- Phase 3: flat PV, 2-deep prefetch ----
    #pragma unroll
    for (int c0 = 0; c0 < 4; ++c0) {
        if (c0 < nchunk) {
            #pragma unroll
            for (int ttl = 0; ttl < 4; ++ttl)
                p_lds[c0 * 16 * PSTR + w * PSTR + ttl * 64 + lane] =
                    (_Float16)(sreg[c0 * 4 + ttl] * inv_z2);
        }
    }

    const int KT = (r0 + 16 + 31) >> 5;   // 1..32 k-tiles of 32 cols, uniform
    const _Float16* vrow = &vtp[(size_t)(w * 16 + n) * SS];
    half8 vb[2] = {};
    if (w < 4) {
        #pragma unroll
        for (int u = 0; u < 2; ++u)
            if (u < KT) vb[u] = *(const half8*)&vrow[u * 32 + quad * 8];
    }
    __syncthreads();

    f32x4 oacc = {0.f, 0.f, 0.f, 0.f};
    if (w < 4) {
        for (int kt0 = 0; kt0 < KT; kt0 += 2) {
            half8 cur0 = vb[0], cur1 = vb[1];
            if (kt0 + 2 < KT) vb[0] = *(const half8*)&vrow[(kt0 + 2) * 32 + quad * 8];
            if (kt0 + 3 < KT) vb[1] = *(const half8*)&vrow[(kt0 + 3) * 32 + quad * 8];
            {
                half8 a = *(const half8*)&p_lds[((kt0 >> 3) * 16 + n) * PSTR +
                                                (kt0 & 7) * 32 + quad * 8];
                oacc = __builtin_amdgcn_mfma_f32_16x16x32_f16(a, cur0, oacc, 0, 0, 0);
            }
            if (kt0 + 1 < KT) {
                const int k = kt0 + 1;
                half8 a = *(const half8*)&p_lds[((k >> 3) * 16 + n) * PSTR +
                                                (k & 7) * 32 + quad * 8];
                oacc = __builtin_amdgcn_mfma_f32_16x16x32_f16(a, cur1, oacc, 0, 0, 0);
            }
        }
        #pragma unroll
        for (int reg = 0; reg < 4; ++reg) {
            const int i = r0 + quad * 4 + reg;
            attn[(((size_t)b * SS + i) * HH + h) * DKK + w * 16 + n] =
                (_Float16)oacc[reg];
        }
    }
}

// ---------------------------------------------------------------------------
extern "C" void kernel_launch(void* const* d_in, const int* in_sizes, int n_in,
                              void* d_out, int out_size, void* d_ws, size_t ws_size,
                              hipStream_t stream) {
    const float* x      = (const float*)d_in[0];
    const float* utT    = (const float*)d_in[1];
    const float* Wk     = (const float*)d_in[2];
    const float* bk     = (const float*)d_in[3];
    const float* Wv     = (const float*)d_in[4];
    const float* bv     = (const float*)d_in[5];
    const float* Wo     = (const float*)d_in[6];
    const float* bo     = (const float*)d_in[7];
    const float* gammas = (const float*)d_in[8];
    float* out = (float*)d_out;

    const size_t NX  = (size_t)NB * SS * DD;   // 4,194,304
    const size_t NW  = (size_t)DD * DD;        // 262,144
    const size_t per = NX;

    _Float16* p      = (_Float16*)d_ws;
    _Float16* xh     = p;  p += NX;
    _Float16* wkh    = p;  p += NW;
    _Float16* wvh    = p;  p += NW;
    _Float16* woh    = p;  p += NW;
    _Float16* q_ws   = p;  p += per;
    _Float16* vt_ws  = p;  p += per;
    _Float16* attn_h = p;  p += per;           // total ~33.5 MB

    const int cvt_blocks = (int)((NX + 3 * NW) / 8 / 256);  // 2432
    cvt_fp16<<<cvt_blocks, dim3(256), 0, stream>>>(
        x, xh, Wk, wkh, Wv, wvh, Wo, woh);

    dim3 g1(64, 8);    // 128x128 tiles, M=8192, N=1024 (q||v)
    gemm_qv<<<g1, dim3(256), 0, stream>>>(xh, wkh, bk, wvh, bv, q_ws, vt_ws);

    dim3 g2(SS / 16, NB * HH);
    attn_mfma<<<g2, dim3(1024), 0, stream>>>(q_ws, vt_ws, utT, gammas, attn_h);

    dim3 g3(64, 4);    // 128x128 tiles, M=8192, N=512
    gemm_out<<<g3, dim3(256), 0, stream>>>(attn_h, woh, bo, out);
}

// Round 12
// 273.266 us; speedup vs baseline: 1.0030x; 1.0030x over previous
//
#include <hip/hip_runtime.h>
#include <math.h>

#define NB   8
#define SS   1024
#define DD   512
#define HH   8
#define DKK  64
#define NEGF (-3.0e38f)
// score scale folded with log2(e): exp(x) == exp2(x*log2e)
#define SC   (0.125f * 1.4426950408889634f)

// OCCUPANCY LEDGER (R0-R11): residency driver is reported VGPR_Count.
// <=32 -> 2 blk/CU; 36-40 -> 1 blk/CU (~1.25x cost). LDS up to 68.6KB has
// NO residency effect at low VGPR (R10). attn FROZEN at R10 body (157.5us).
// R11 (BK 32->64, half the barrier PAIRS) = null -> barrier COUNT is not
// the GEMM cost. R12 tests barrier PLACEMENT: 2-phase pipeline (stage next
// tile BEFORE compute, ONE barrier/step) so the vmcnt drain lands after
// compute and load latency is overlapped instead of fully exposed.
#define QSTR 88             // halves; q tile stride
#define SCHUNK (16 * 256)   // floats per score chunk buffer (XOR swizzled)
#define PSTR 280            // halves; attn p rows (phase 3, aliased)

typedef _Float16 half8 __attribute__((ext_vector_type(8)));
typedef float    f32x4 __attribute__((ext_vector_type(4)));

// async 16B/lane global->LDS (wave-uniform LDS base + lane*16)
#define GLDS16(g, l) __builtin_amdgcn_global_load_lds( \
    (const __attribute__((address_space(1))) void*)(g), \
    (__attribute__((address_space(3))) void*)(l), 16, 0, 0)

// ---------------------------------------------------------------------------
// DPP helpers: full-rate VALU cross-lane (no ds_bpermute).
// ---------------------------------------------------------------------------
template<int CTRL, int RM, int BM, bool BC>
__device__ __forceinline__ float dpp_f(float x) {
    return __builtin_bit_cast(float,
        __builtin_amdgcn_update_dpp(0, __builtin_bit_cast(int, x),
                                    CTRL, RM, BM, BC));
}

// inclusive 64-lane prefix sum: row_shr 1/2/4/8 then row_bcast:15 (rows 1,3)
// and row_bcast:31 (rows 2,3). old=0 so masked/invalid lanes add 0.
__device__ __forceinline__ float scan64(float x) {
    x += dpp_f<0x111, 0xf, 0xf, true >(x);   // row_shr:1
    x += dpp_f<0x112, 0xf, 0xf, true >(x);   // row_shr:2
    x += dpp_f<0x114, 0xf, 0xf, true >(x);   // row_shr:4
    x += dpp_f<0x118, 0xf, 0xf, true >(x);   // row_shr:8
    x += dpp_f<0x142, 0xa, 0xf, false>(x);   // row_bcast:15 -> rows 1,3
    x += dpp_f<0x143, 0xc, 0xf, false>(x);   // row_bcast:31 -> rows 2,3
    return x;
}

__device__ __forceinline__ float redsum64(float x) {
    x += dpp_f<0xB1,  0xf, 0xf, true>(x);    // quad_perm [1,0,3,2]  (xor 1)
    x += dpp_f<0x4E,  0xf, 0xf, true>(x);    // quad_perm [2,3,0,1]  (xor 2)
    x += dpp_f<0x141, 0xf, 0xf, true>(x);    // row_half_mirror      (xor 4)
    x += dpp_f<0x140, 0xf, 0xf, true>(x);    // row_mirror           (xor 8)
    x += __shfl_xor(x, 16);
    x += __shfl_xor(x, 32);
    return x;
}

__device__ __forceinline__ float bcast63(float x) {
    return __builtin_bit_cast(float,
        __builtin_amdgcn_readlane(__builtin_bit_cast(int, x), 63));
}

// ---------------------------------------------------------------------------
// cvt: x, Wk, Wv, Wo (fp32) -> fp16 buffers. 8 elems/thread.
// ---------------------------------------------------------------------------
__global__ __launch_bounds__(256) void cvt_fp16(
    const float* __restrict__ x,  _Float16* __restrict__ xh,
    const float* __restrict__ wk, _Float16* __restrict__ wkh,
    const float* __restrict__ wv, _Float16* __restrict__ wvh,
    const float* __restrict__ wo, _Float16* __restrict__ woh)
{
    const size_t NX = (size_t)NB * SS * DD;   // 4194304
    const size_t NW = (size_t)DD * DD;        // 262144
    size_t f = ((size_t)blockIdx.x * 256 + threadIdx.x) * 8;
    const float* src; _Float16* dst; size_t off;
    if (f < NX)               { src = x;  dst = xh;  off = f; }
    else if (f < NX + NW)     { src = wk; dst = wkh; off = f - NX; }
    else if (f < NX + 2*NW)   { src = wv; dst = wvh; off = f - NX - 2*NW + NW; }
    else                      { src = wo; dst = woh; off = f - NX - 2*NW; }
    float4 f0 = *(const float4*)&src[off];
    float4 f1 = *(const float4*)&src[off + 4];
    half8 hv = {(_Float16)f0.x,(_Float16)f0.y,(_Float16)f0.z,(_Float16)f0.w,
                (_Float16)f1.x,(_Float16)f1.y,(_Float16)f1.z,(_Float16)f1.w};
    *(half8*)&dst[off] = hv;
}

// ---------------------------------------------------------------------------
// GEMM #1 — R12: 2-phase pipelined (stage tile k+1 into the other LDS
// buffer BEFORE computing tile k; ONE __syncthreads per step — its vmcnt
// drain lands after the 32-MFMA compute, overlapping load latency).
// BK=64, 128x128 tile. Accumulation order bit-identical to R11.
// q = xh@Wk^T + bk -> fp16 [b,h,s,dk]; v = xh@Wv^T + bv -> fp16 [b,h,dk,s].
// ---------------------------------------------------------------------------
__global__ __launch_bounds__(256) void gemm_qv(
    const _Float16* __restrict__ xh,
    const _Float16* __restrict__ wkh, const float* __restrict__ bk,
    const _Float16* __restrict__ wvh, const float* __restrict__ bv,
    _Float16* __restrict__ q_ws, _Float16* __restrict__ vt_ws)
{
    __shared__ __align__(16) _Float16 Ah[2][128 * 64];   // 2 x 16 KB
    __shared__ __align__(16) _Float16 Bh[2][128 * 64];   // 2 x 16 KB

    const int m0  = blockIdx.x * 128;
    const int n0c = blockIdx.y * 128;
    const bool is_v = (n0c >= DD);
    const _Float16* __restrict__ Wp = is_v ? wvh : wkh;
    const float*    __restrict__ bp = is_v ? bv : bk;
    const int n0 = n0c & (DD - 1);

    const int tid  = threadIdx.x;
    const int w    = tid >> 6;
    const int lane = tid & 63;
    const int quad = lane >> 4;
    const int n    = lane & 15;
    const int wm   = w >> 1, wn = w & 1;

    // DMA coords: ci covers 128 rows x 64 cols; row = ci>>3, col8 = (ci&7)*8
    const int ci  = (w * 4) * 64 + lane;   // base for c=0; c adds 64 to ci
    f32x4 acc[4][4] = {};

    // prologue: stage k0=0 into buffer 0
    #pragma unroll
    for (int c = 0; c < 4; ++c) {
        const int cc = ci + c * 64;
        const int r  = cc >> 3, co = (cc & 7) * 8;
        GLDS16(&xh[(size_t)(m0 + r) * DD + co], &Ah[0][(w * 4 + c) * 512]);
        GLDS16(&Wp[(size_t)(n0 + r) * DD + co], &Bh[0][(w * 4 + c) * 512]);
    }
    __syncthreads();   // drain -> buf0 ready

    #pragma unroll
    for (int step = 0; step < 8; ++step) {
        const int cur = step & 1;
        const int nxt = cur ^ 1;
        const int k0  = step * 64;
        if (step < 7) {
            #pragma unroll
            for (int c = 0; c < 4; ++c) {
                const int cc = ci + c * 64;
                const int r  = cc >> 3, co = (cc & 7) * 8;
                GLDS16(&xh[(size_t)(m0 + r) * DD + k0 + 64 + co],
                       &Ah[nxt][(w * 4 + c) * 512]);
                GLDS16(&Wp[(size_t)(n0 + r) * DD + k0 + 64 + co],
                       &Bh[nxt][(w * 4 + c) * 512]);
            }
        }
        #pragma unroll
        for (int kf = 0; kf < 2; ++kf) {
            half8 af[4], bf[4];
            #pragma unroll
            for (int mi = 0; mi < 4; ++mi)
                af[mi] = *(const half8*)&Ah[cur][(wm*64 + mi*16 + n) * 64 + kf*32 + quad*8];
            #pragma unroll
            for (int ni = 0; ni < 4; ++ni)
                bf[ni] = *(const half8*)&Bh[cur][(wn*64 + ni*16 + n) * 64 + kf*32 + quad*8];
            #pragma unroll
            for (int mi = 0; mi < 4; ++mi)
                #pragma unroll
                for (int ni = 0; ni < 4; ++ni)
                    acc[mi][ni] = __builtin_amdgcn_mfma_f32_16x16x32_f16(
                        af[mi], bf[ni], acc[mi][ni], 0, 0, 0);
        }
        __syncthreads();   // reads of buf[cur] done; in-flight stages drained
    }

    #pragma unroll
    for (int mi = 0; mi < 4; ++mi) {
        #pragma unroll
        for (int ni = 0; ni < 4; ++ni) {
            const int col = n0 + wn*64 + ni*16 + n;   // 0..511
            const int h   = col >> 6;
            const int dk  = col & 63;
            const float bias = bp[col];
            const int gbase = m0 + wm*64 + mi*16 + quad*4;
            const int bidx  = gbase >> 10;
            const int sr    = gbase & (SS - 1);
            if (!is_v) {
                #pragma unroll
                for (int reg = 0; reg < 4; ++reg)
                    q_ws[((size_t)(bidx * HH + h) * SS + sr + reg) * DKK + dk] =
                        (_Float16)(acc[mi][ni][reg] + bias);
            } else {
                _Float16 h4[4];
                #pragma unroll
                for (int reg = 0; reg < 4; ++reg)
                    h4[reg] = (_Float16)(acc[mi][ni][reg] + bias);
                *(uint2*)&vt_ws[((size_t)(bidx * HH + h) * DKK + dk) * SS + sr] =
                    *(uint2*)h4;
            }
        }
    }
}

// ---------------------------------------------------------------------------
// GEMM #2 — R12: same 2-phase pipeline. out = attn_h @ Wo^T + bo.
// ---------------------------------------------------------------------------
__global__ __launch_bounds__(256) void gemm_out(
    const _Float16* __restrict__ A,
    const _Float16* __restrict__ woh, const float* __restrict__ bo,
    float* __restrict__ out)
{
    __shared__ __align__(16) _Float16 Ah[2][128 * 64];
    __shared__ __align__(16) _Float16 Bh[2][128 * 64];

    const int m0 = blockIdx.x * 128;
    const int n0 = blockIdx.y * 128;

    const int tid  = threadIdx.x;
    const int w    = tid >> 6;
    const int lane = tid & 63;
    const int quad = lane >> 4;
    const int n    = lane & 15;
    const int wm   = w >> 1, wn = w & 1;

    const int ci = (w * 4) * 64 + lane;
    f32x4 acc[4][4] = {};

    #pragma unroll
    for (int c = 0; c < 4; ++c) {
        const int cc = ci + c * 64;
        const int r  = cc >> 3, co = (cc & 7) * 8;
        GLDS16(&A[(size_t)(m0 + r) * DD + co],   &Ah[0][(w * 4 + c) * 512]);
        GLDS16(&woh[(size_t)(n0 + r) * DD + co], &Bh[0][(w * 4 + c) * 512]);
    }
    __syncthreads();

    #pragma unroll
    for (int step = 0; step < 8; ++step) {
        const int cur = step & 1;
        const int nxt = cur ^ 1;
        const int k0  = step * 64;
        if (step < 7) {
            #pragma unroll
            for (int c = 0; c < 4; ++c) {
                const int cc = ci + c * 64;
                const int r  = cc >> 3, co = (cc & 7) * 8;
                GLDS16(&A[(size_t)(m0 + r) * DD + k0 + 64 + co],
                       &Ah[nxt][(w * 4 + c) * 512]);
                GLDS16(&woh[(size_t)(n0 + r) * DD + k0 + 64 + co],
                       &Bh[nxt][(w * 4 + c) * 512]);
            }
        }
        #pragma unroll
        for (int kf = 0; kf < 2; ++kf) {
            half8 af[4], bf[4];
            #pragma unroll
            for (int mi = 0; mi < 4; ++mi)
                af[mi] = *(const half8*)&Ah[cur][(wm*64 + mi*16 + n) * 64 + kf*32 + quad*8];
            #pragma unroll
            for (int ni = 0; ni < 4; ++ni)
                bf[ni] = *(const half8*)&Bh[cur][(wn*64 + ni*16 + n) * 64 + kf*32 + quad*8];
            #pragma unroll
            for (int mi = 0; mi < 4; ++mi)
                #pragma unroll
                for (int ni = 0; ni < 4; ++ni)
                    acc[mi][ni] = __builtin_amdgcn_mfma_f32_16x16x32_f16(
                        af[mi], bf[ni], acc[mi][ni], 0, 0, 0);
        }
        __syncthreads();
    }

    #pragma unroll
    for (int mi = 0; mi < 4; ++mi) {
        #pragma unroll
        for (int ni = 0; ni < 4; ++ni) {
            const int col  = n0 + wn*64 + ni*16 + n;
            const float bias = bo[col];
            const int gbase = m0 + wm*64 + mi*16 + quad*4;
            #pragma unroll
            for (int reg = 0; reg < 4; ++reg)
                out[(size_t)(gbase + reg) * DD + col] = acc[mi][ni][reg] + bias;
        }
    }
}

// ---------------------------------------------------------------------------
// MFMA attention — R10 body, FROZEN (157.5us, VGPR 28, 2 blk/CU):
// single-barrier Phase 1 (#pragma unroll 1 dynamic loop, per-chunk buffers),
// swapped-operand QK^T, XOR swizzle, R9 Phase 2 (no cs[16]), flat PV.
// Known-toxic (do not retry): forced 2-blk/CU launch_bounds (R3, spill);
// reported VGPR > 32 (R5-R8); sched_barrier-pinned raw barriers + manual
// cross-barrier prefetch (R5, m141); 16-wave PV + o_red; utT fold + tmax;
// 8-wave blocks (old session).
// ---------------------------------------------------------------------------
__global__ __launch_bounds__(1024) void attn_mfma(
    const _Float16* __restrict__ q,   // [B,H,S,DK] fp16 (K = Q)
    const _Float16* __restrict__ vt,  // [B,H,DK,S] fp16 (V transposed)
    const float* __restrict__ utT,    // [B,S,S]
    const float* __restrict__ gammas, // [H]
    _Float16* __restrict__ attn)      // [B,S,H,DK] fp16
{
    // phase 1: 4 x SCHUNK f32 = 65536 B; phase 3 aliases 4x16xPSTR halves
    // (35840 B) inside it. + q_lds 2816 B = 68352 B total.
    __shared__ __align__(16) unsigned char smem[4 * SCHUNK * 4];
    __shared__ __align__(16) _Float16 q_lds[16 * QSTR];
    float*    s_lds = (float*)smem;
    _Float16* p_lds = (_Float16*)smem;

    const int tid  = threadIdx.x;
    const int w    = tid >> 6;
    const int lane = tid & 63;
    const int quad = lane >> 4;
    const int n    = lane & 15;
    const int bh   = blockIdx.y;
    const int b    = bh >> 3;
    const int h    = bh & 7;
    // heavy-first (LPT): largest r0 dispatched first, light blocks fill tail
    const int r0   = ((SS / 16 - 1) - blockIdx.x) * 16;

    const _Float16* __restrict__ kq  = q  + (size_t)bh * SS * DKK;
    const _Float16* __restrict__ vtp = vt + (size_t)bh * DKK * SS;

    const int nchunk = (r0 + 16 + 255) >> 8;   // 1..4, block-uniform
    const int nt     = nchunk * 4;
    const int i_lane = r0 + n;   // q-row owned by this lane in phase 1

    // stage Q tile into LDS (keeps qa fragments out of long-lived VGPRs)
    if (tid < 256) {
        const int row = tid >> 4;
        const int c   = tid & 15;
        *(uint2*)&q_lds[row * QSTR + c * 4] =
            *(const uint2*)&kq[(size_t)(r0 + row) * DKK + c * 4];
    }
    __syncthreads();

    const float* __restrict__ utrow = &utT[((size_t)b * SS + i_lane) * SS];
    const int scol = (w * 16 + quad * 4) ^ ((n & 7) << 2);   // store swizzle
    const int pcol = lane ^ ((w & 7) << 2);                  // pull swizzle

    // ---- Phase 1: dynamic loop, per-chunk buffers, NO inter-chunk barrier
    #pragma unroll 1
    for (int c0 = 0; c0 < nchunk; ++c0) {
        const int jbase = c0 * 256 + w * 16;
        f32x4 v;
        if (jbase <= r0 + 15) {        // wave-uniform guard
            half8 qa0 = *(const half8*)&q_lds[n * QSTR + quad * 8];
            half8 qa1 = *(const half8*)&q_lds[n * QSTR + 32 + quad * 8];
            const _Float16* krow = &kq[(size_t)(jbase + n) * DKK];
            half8 k0 = *(const half8*)&krow[quad * 8];
            half8 k1 = *(const half8*)&krow[32 + quad * 8];
            f32x4 ut = *(const f32x4*)&utrow[jbase + quad * 4];
            f32x4 d = {0.f, 0.f, 0.f, 0.f};
            d = __builtin_amdgcn_mfma_f32_16x16x32_f16(k0, qa0, d, 0, 0, 0);
            d = __builtin_amdgcn_mfma_f32_16x16x32_f16(k1, qa1, d, 0, 0, 0);
            #pragma unroll
            for (int reg = 0; reg < 4; ++reg) {
                const int j = jbase + quad * 4 + reg;
                v[reg] = (j <= i_lane) ? d[reg] * SC * ut[reg] : NEGF;
            }
        } else {
            v = (f32x4){NEGF, NEGF, NEGF, NEGF};
        }
        *(f32x4*)&s_lds[c0 * SCHUNK + n * 256 + scol] = v;
    }
    __syncthreads();   // ONE barrier for the whole phase

    float sreg[16];
    #pragma unroll
    for (int c0 = 0; c0 < 4; ++c0) {
        if (c0 < nchunk) {
            #pragma unroll
            for (int ttl = 0; ttl < 4; ++ttl)
                sreg[c0 * 4 + ttl] =
                    s_lds[c0 * SCHUNK + w * 256 + ttl * 64 + pcol];
        }
    }

    // ---- Phase 2 ----
    const int i_row = r0 + w;
    const int ntw_u = (i_row >> 6) + 1;          // tiles intersecting causal
    const int ntw   = (nt < ntw_u) ? nt : ntw_u; // wave-uniform

    // pass A: z1 = row total of e — plain sum per lane + one butterfly.
    float z1acc = 0.f;
    #pragma unroll
    for (int t2 = 0; t2 < 16; ++t2)
        if (t2 < ntw) z1acc += __builtin_amdgcn_exp2f(sreg[t2]);
    const float z1     = redsum64(z1acc);
    const float inv_z1 = 1.0f / z1;

    const float g     = gammas[h];
    const float gl2   = -log1pf(__expf(g)) * 1.4426950408889634f; // gamma*log2e
    const float flane = (float)lane;

    // pass B: inline scan (e recomputed bit-identically), decay, numerator
    float carry = 0.f;
    float z2 = 0.f;
    #pragma unroll
    for (int t2 = 0; t2 < 16; ++t2) {
        if (t2 < ntw) {
            const float e  = __builtin_amdgcn_exp2f(sreg[t2]); // masked -> 0
            const float xv = scan64(e);
            const float cs = carry + xv;
            carry += bcast63(xv);
            const float pe = (float)(i_row - t2 * 64) - flane;  // <0 only masked
            const float dd = fmaxf((z1 - cs) * pe, 0.0f) * inv_z1;
            float te = __builtin_amdgcn_exp2f(__builtin_amdgcn_sqrtf(dd) * gl2);
            te = fmaxf(te, 1e-5f);            // gamma<0 -> te<=1, no hi clamp
            const float p = __builtin_amdgcn_exp2f(sreg[t2] * te); // masked -> 0
            sreg[t2] = p;
            z2 += p;
        } else {
            sreg[t2] = 0.f;                   // tiles beyond causal extent
        }
    }
    z2 = redsum64(z2);
    const float inv_z2 = 1.0f / z2;

    __syncthreads();   // all phase-1 s_lds pulls complete before p writes

    // ---- Phase 3: flat PV, 2-deep prefetch ----
    #pragma unroll
    for (int c0 = 0; c0 < 4; ++c0) {
        if (c0 < nchunk) {
            #pragma unroll
            for (int ttl = 0; ttl < 4; ++ttl)
                p_lds[c0 * 16 * PSTR + w * PSTR + ttl * 64 + lane] =
                    (_Float16)(sreg[c0 * 4 + ttl] * inv_z2);
        }
    }

    const int KT = (r0 + 16 + 31) >> 5;   // 1..32 k-tiles of 32 cols, uniform
    const _Float16* vrow = &vtp[(size_t)(w * 16 + n) * SS];
    half8 vb[2] = {};
    if (w < 4) {
        #pragma unroll
        for (int u = 0; u < 2; ++u)
            if (u < KT) vb[u] = *(const half8*)&vrow[u * 32 + quad * 8];
    }
    __syncthreads();

    f32x4 oacc = {0.f, 0.f, 0.f, 0.f};
    if (w < 4) {
        for (int kt0 = 0; kt0 < KT; kt0 += 2) {
            half8 cur0 = vb[0], cur1 = vb[1];
            if (kt0 + 2 < KT) vb[0] = *(const half8*)&vrow[(kt0 + 2) * 32 + quad * 8];
            if (kt0 + 3 < KT) vb[1] = *(const half8*)&vrow[(kt0 + 3) * 32 + quad * 8];
            {
                half8 a = *(const half8*)&p_lds[((kt0 >> 3) * 16 + n) * PSTR +
                                                (kt0 & 7) * 32 + quad * 8];
                oacc = __builtin_amdgcn_mfma_f32_16x16x32_f16(a, cur0, oacc, 0, 0, 0);
            }
            if (kt0 + 1 < KT) {
                const int k = kt0 + 1;
                half8 a = *(const half8*)&p_lds[((k >> 3) * 16 + n) * PSTR +
                                                (k & 7) * 32 + quad * 8];
                oacc = __builtin_amdgcn_mfma_f32_16x16x32_f16(a, cur1, oacc, 0, 0, 0);
            }
        }
        #pragma unroll
        for (int reg = 0; reg < 4; ++reg) {
            const int i = r0 + quad * 4 + reg;
            attn[(((size_t)b * SS + i) * HH + h) * DKK + w * 16 + n] =
                (_Float16)oacc[reg];
        }
    }
}

// ---------------------------------------------------------------------------
extern "C" void kernel_launch(void* const* d_in, const int* in_sizes, int n_in,
                              void* d_out, int out_size, void* d_ws, size_t ws_size,
                              hipStream_t stream) {
    const float* x      = (const float*)d_in[0];
    const float* utT    = (const float*)d_in[1];
    const float* Wk     = (const float*)d_in[2];
    const float* bk     = (const float*)d_in[3];
    const float* Wv     = (const float*)d_in[4];
    const float* bv     = (const float*)d_in[5];
    const float* Wo     = (const float*)d_in[6];
    const float* bo     = (const float*)d_in[7];
    const float* gammas = (const float*)d_in[8];
    float* out = (float*)d_out;

    const size_t NX  = (size_t)NB * SS * DD;   // 4,194,304
    const size_t NW  = (size_t)DD * DD;        // 262,144
    const size_t per = NX;

    _Float16* p      = (_Float16*)d_ws;
    _Float16* xh     = p;  p += NX;
    _Float16* wkh    = p;  p += NW;
    _Float16* wvh    = p;  p += NW;
    _Float16* woh    = p;  p += NW;
    _Float16* q_ws   = p;  p += per;
    _Float16* vt_ws  = p;  p += per;
    _Float16* attn_h = p;  p += per;           // total ~33.5 MB

    const int cvt_blocks = (int)((NX + 3 * NW) / 8 / 256);  // 2432
    cvt_fp16<<<cvt_blocks, dim3(256), 0, stream>>>(
        x, xh, Wk, wkh, Wv, wvh, Wo, woh);

    dim3 g1(64, 8);    // 128x128 tiles, M=8192, N=1024 (q||v)
    gemm_qv<<<g1, dim3(256), 0, stream>>>(xh, wkh, bk, wvh, bv, q_ws, vt_ws);

    dim3 g2(SS / 16, NB * HH);
    attn_mfma<<<g2, dim3(1024), 0, stream>>>(q_ws, vt_ws, utT, gammas, attn_h);

    dim3 g3(64, 4);    // 128x128 tiles, M=8192, N=512
    gemm_out<<<g3, dim3(256), 0, stream>>>(attn_h, woh, bo, out);
}